// Round 1
// 1275.953 us; speedup vs baseline: 1.0728x; 1.0728x over previous
//
#include <hip/hip_runtime.h>
#include <stdint.h>

#define T_TOK 4096
#define H_DIM 2048
#define I_DIM 4096
#define N_EXP 8

typedef __attribute__((ext_vector_type(8))) short bf16x8;     // MFMA A/B frag (8 bf16)
typedef __attribute__((ext_vector_type(4))) float f32x4;      // MFMA C/D frag
typedef __attribute__((ext_vector_type(8))) unsigned short u16x8;

__device__ __forceinline__ unsigned short f2bf(float x) {
    union { float f; unsigned u; } v; v.f = x;
    unsigned r = v.u + 0x7FFF + ((v.u >> 16) & 1);   // RNE
    return (unsigned short)(r >> 16);
}

// Direct global->LDS async copy, 16B per lane. LDS dest = wave-uniform base + lane*16.
__device__ __forceinline__ void async_cp16(const void* g, const unsigned short* lds_base) {
    __builtin_amdgcn_global_load_lds(
        (const __attribute__((address_space(1))) unsigned*)g,
        (__attribute__((address_space(3))) unsigned*)(unsigned)(uintptr_t)lds_base,
        16, 0, 0);
}

// ---------------- routing: top-2 + softmax + bucketize (single block) ----------
__global__ void routing_kernel(const float* __restrict__ logits,
                               int* __restrict__ counts, int* __restrict__ offsets,
                               int* __restrict__ btok, float* __restrict__ bw,
                               int* __restrict__ tok2slot) {
    __shared__ int s_cnt[N_EXP];
    __shared__ int s_off[N_EXP];
    __shared__ int s_cur[N_EXP];
    const int tid = threadIdx.x;   // 256 threads, 16 tokens each
    if (tid < N_EXP) s_cnt[tid] = 0;
    __syncthreads();

    int e0a[16], e1a[16]; float w0a[16], w1a[16];
    #pragma unroll
    for (int it = 0; it < 16; ++it) {
        int t = tid + it * 256;
        float l[8];
        #pragma unroll
        for (int e = 0; e < 8; ++e) l[e] = logits[t * 8 + e];
        int b0 = 0; float v0 = l[0];
        #pragma unroll
        for (int e = 1; e < 8; ++e) if (l[e] > v0) { v0 = l[e]; b0 = e; }
        int b1 = (b0 == 0) ? 1 : 0; float v1 = l[b1];
        #pragma unroll
        for (int e = 0; e < 8; ++e) if (e != b0 && l[e] > v1) { v1 = l[e]; b1 = e; }
        float w0 = 1.0f / (1.0f + __expf(v1 - v0));
        e0a[it] = b0; e1a[it] = b1; w0a[it] = w0; w1a[it] = 1.0f - w0;
        atomicAdd(&s_cnt[b0], 1);
        atomicAdd(&s_cnt[b1], 1);
    }
    __syncthreads();
    if (tid == 0) {
        int acc = 0;
        for (int e = 0; e < N_EXP; ++e) { s_off[e] = acc; s_cur[e] = acc; acc += s_cnt[e]; }
    }
    __syncthreads();
    if (tid < N_EXP) { counts[tid] = s_cnt[tid]; offsets[tid] = s_off[tid]; }
    #pragma unroll
    for (int it = 0; it < 16; ++it) {
        int t = tid + it * 256;
        int p0 = atomicAdd(&s_cur[e0a[it]], 1);
        btok[p0] = t; bw[p0] = w0a[it];
        int p1 = atomicAdd(&s_cur[e1a[it]], 1);
        btok[p1] = t; bw[p1] = w1a[it];
        tok2slot[2 * t] = p0;
        tok2slot[2 * t + 1] = p1;
    }
}

// ---------------- fp32 -> bf16 convert (generic) -----------------------------
__global__ void cvt_kernel(const float* __restrict__ x, unsigned short* __restrict__ xb) {
    int i = blockIdx.x * blockDim.x + threadIdx.x;   // over float4s
    float4 v = ((const float4*)x)[i];
    ushort4 o;
    o.x = f2bf(v.x); o.y = f2bf(v.y); o.z = f2bf(v.z); o.w = f2bf(v.w);
    ((ushort4*)xb)[i] = o;
}

// =====================  PATH A: pipelined bf16 GEMMs =========================
//
// Deep-pipelined schedule (T3+T4+T5 from the technique catalog, adapted):
//   - 512 threads (8 waves), BM=256, BK=32, 3-deep LDS ring buffer.
//   - 2-tile prefetch lookahead: while computing tile t (buf t%3), stage tile
//     t+2 (buf (t+2)%3). Tile t+1 was fully staged during t-1, so the boundary
//     wait is the COUNTED vmcnt(4) (t+2's 4 loads may stay in flight) -- never
//     a drain in the main loop.
//   - Per K-tile: 2 phases, each {ds_read frags | 2 global_load_lds | s_barrier
//     | setprio(1) 16xMFMA setprio(0) | s_barrier}.
//   - LDS XOR swizzle: staging pre-swizzles the GLOBAL source chunk
//     ((lane&3)^((lane>>3)&3)) with a linear LDS dest (global_load_lds
//     requirement), reads use slot q^((c>>1)&3): 8-way conflict -> 2-way (free).

// GEMM1: h[slot,i] = silu(x@W1^T) * (x@W3^T).  BM=256 x BN=128, K=H_DIM.
__global__ __launch_bounds__(512, 2)
void gemm1p_kernel(const unsigned short* __restrict__ Xb,
                   const unsigned short* __restrict__ W1b,
                   const unsigned short* __restrict__ W3b,
                   const int* __restrict__ counts,
                   const int* __restrict__ offsets,
                   const int* __restrict__ btok,
                   unsigned short* __restrict__ hbuf) {
    const int e = blockIdx.z;
    const int ne = counts[e];
    const int mt = blockIdx.y;
    if (mt * 256 >= ne) return;
    const int nt = blockIdx.x;
    const int off = offsets[e];

    __shared__ unsigned short sA[3][256 * 32];    // 48 KB
    __shared__ unsigned short sB1[3][128 * 32];   // 24 KB
    __shared__ unsigned short sB3[3][128 * 32];   // 24 KB
    __shared__ int s_tok[256];

    const int tid = threadIdx.x;
    if (tid < 256) {
        int slot = mt * 256 + tid;
        s_tok[tid] = btok[off + ((slot < ne) ? slot : (ne - 1))];  // clamp; epilogue masks
    }
    __syncthreads();

    const int lane = tid & 63;
    const int wv = tid >> 6;
    const int wm = (wv >> 1) << 6;   // 0,64,128,192 (4 M-waves)
    const int wn = (wv & 1) << 6;    // 0,64         (2 N-waves)
    const int q = lane >> 4;
    const int c = lane & 15;
    const int xq = q ^ ((c >> 1) & 3);          // swizzled read slot

    const int aoff = (wm + c) * 32 + xq * 8;    // elements within a 32-col tile
    const int boff = (wn + c) * 32 + xq * 8;

    // staging: wave wv covers 16 rows/round; lane -> row wv*16+(lane>>2), slot lane&3
    const int srow = wv * 16 + (lane >> 2);           // 0..127
    const int sg = (lane & 3) ^ ((lane >> 3) & 3);    // pre-swizzled source chunk

    const unsigned short* gA0 = Xb + (size_t)s_tok[srow] * H_DIM + sg * 8;
    const unsigned short* gA1 = Xb + (size_t)s_tok[srow + 128] * H_DIM + sg * 8;
    const size_t wrow = (size_t)e * I_DIM + nt * 128 + srow;
    const unsigned short* gB1 = W1b + wrow * H_DIM + sg * 8;
    const unsigned short* gB3 = W3b + wrow * H_DIM + sg * 8;

    const int dofsA0 = wv * 512;            // LDS element offsets (wave-uniform)
    const int dofsA1 = 4096 + wv * 512;
    const int dofsB  = wv * 512;

    f32x4 accg[4][4], accu[4][4];
    const f32x4 zero = {0.0f, 0.0f, 0.0f, 0.0f};
    #pragma unroll
    for (int i = 0; i < 4; ++i)
        #pragma unroll
        for (int j = 0; j < 4; ++j) { accg[i][j] = zero; accu[i][j] = zero; }

    // prologue: stage tiles 0 and 1 (4 loads each)
    async_cp16(gA0,      &sA[0][dofsA0]);
    async_cp16(gB1,      &sB1[0][dofsB]);
    async_cp16(gA1,      &sA[0][dofsA1]);
    async_cp16(gB3,      &sB3[0][dofsB]);
    async_cp16(gA0 + 32, &sA[1][dofsA0]);
    async_cp16(gB1 + 32, &sB1[1][dofsB]);
    async_cp16(gA1 + 32, &sA[1][dofsA1]);
    async_cp16(gB3 + 32, &sB3[1][dofsB]);
    asm volatile("s_waitcnt vmcnt(4)" ::: "memory");   // tile 0 landed
    __builtin_amdgcn_s_barrier();
    __builtin_amdgcn_sched_barrier(0);

    const int NT = H_DIM / 32;   // 64
    for (int t = 0; t < NT; ++t) {
        const int cur = t % 3;
        const int nx2 = (t + 2) % 3;
        const bool stg = (t + 2) < NT;
        const int kt2 = (t + 2) * 32;

        // ---- phase A: gate ----
        bf16x8 af[4], b1f[4];
        #pragma unroll
        for (int i = 0; i < 4; ++i) af[i] = *(const bf16x8*)(&sA[cur][aoff + i * 512]);
        #pragma unroll
        for (int j = 0; j < 4; ++j) b1f[j] = *(const bf16x8*)(&sB1[cur][boff + j * 512]);
        if (stg) {
            async_cp16(gA0 + kt2, &sA[nx2][dofsA0]);
            async_cp16(gB1 + kt2, &sB1[nx2][dofsB]);
        }
        __builtin_amdgcn_s_barrier();
        __builtin_amdgcn_s_setprio(1);
        #pragma unroll
        for (int i = 0; i < 4; ++i)
            #pragma unroll
            for (int j = 0; j < 4; ++j)
                accg[i][j] = __builtin_amdgcn_mfma_f32_16x16x32_bf16(af[i], b1f[j], accg[i][j], 0, 0, 0);
        __builtin_amdgcn_s_setprio(0);
        __builtin_amdgcn_s_barrier();

        // ---- phase B: up (reuses af) ----
        bf16x8 b3f[4];
        #pragma unroll
        for (int j = 0; j < 4; ++j) b3f[j] = *(const bf16x8*)(&sB3[cur][boff + j * 512]);
        if (stg) {
            async_cp16(gA1 + kt2, &sA[nx2][dofsA1]);
            async_cp16(gB3 + kt2, &sB3[nx2][dofsB]);
        }
        __builtin_amdgcn_s_barrier();
        __builtin_amdgcn_s_setprio(1);
        #pragma unroll
        for (int i = 0; i < 4; ++i)
            #pragma unroll
            for (int j = 0; j < 4; ++j)
                accu[i][j] = __builtin_amdgcn_mfma_f32_16x16x32_bf16(af[i], b3f[j], accu[i][j], 0, 0, 0);
        __builtin_amdgcn_s_setprio(0);

        // ---- K-tile boundary: counted wait, tile t+1 guaranteed landed ----
        if (t + 1 < NT) {
            if (stg) asm volatile("s_waitcnt vmcnt(4)" ::: "memory");
            else     asm volatile("s_waitcnt vmcnt(0)" ::: "memory");  // tail only
            __builtin_amdgcn_s_barrier();
            __builtin_amdgcn_sched_barrier(0);
        }
    }

    // epilogue: silu(gate)*up -> bf16
    #pragma unroll
    for (int i = 0; i < 4; ++i) {
        #pragma unroll
        for (int r = 0; r < 4; ++r) {
            int mloc = wm + i * 16 + q * 4 + r;
            int slot = mt * 256 + mloc;
            if (slot < ne) {
                size_t rowbase = (size_t)(off + slot) * I_DIM + nt * 128 + wn;
                #pragma unroll
                for (int j = 0; j < 4; ++j) {
                    float g = accg[i][j][r];
                    float u = accu[i][j][r];
                    float val = (g / (1.0f + __expf(-g))) * u;
                    hbuf[rowbase + j * 16 + c] = f2bf(val);
                }
            }
        }
    }
}

// GEMM2: y[slot,h] = h[slot] @ W2^T.  BM=256 x BN=256, K=I_DIM.
__global__ __launch_bounds__(512, 2)
void gemm2p_kernel(const unsigned short* __restrict__ hbuf,
                   const unsigned short* __restrict__ W2b,
                   const int* __restrict__ counts,
                   const int* __restrict__ offsets,
                   float* __restrict__ ybuf) {
    const int e = blockIdx.z;
    const int ne = counts[e];
    const int mt = blockIdx.y;
    if (mt * 256 >= ne) return;
    const int nt = blockIdx.x;
    const int off = offsets[e];

    __shared__ unsigned short sA[3][256 * 32];   // 48 KB
    __shared__ unsigned short sB[3][256 * 32];   // 48 KB

    const int tid = threadIdx.x;
    const int lane = tid & 63;
    const int wv = tid >> 6;
    const int wm = (wv >> 2) << 7;   // 0,128  (2 M-waves)
    const int wn = (wv & 3) << 6;    // 0,64,128,192 (4 N-waves)
    const int q = lane >> 4;
    const int c = lane & 15;
    const int xq = q ^ ((c >> 1) & 3);

    const int aoff = (wm + c) * 32 + xq * 8;
    const int boff = (wn + c) * 32 + xq * 8;

    const int srow = wv * 16 + (lane >> 2);
    const int sg = (lane & 3) ^ ((lane >> 3) & 3);

    int slot0 = mt * 256 + srow;        if (slot0 >= ne) slot0 = ne - 1;
    int slot1 = mt * 256 + srow + 128;  if (slot1 >= ne) slot1 = ne - 1;
    const unsigned short* gA0 = hbuf + (size_t)(off + slot0) * I_DIM + sg * 8;
    const unsigned short* gA1 = hbuf + (size_t)(off + slot1) * I_DIM + sg * 8;
    const size_t wrow = (size_t)e * H_DIM + nt * 256 + srow;
    const unsigned short* gB0 = W2b + wrow * I_DIM + sg * 8;
    const unsigned short* gB1 = W2b + (wrow + 128) * I_DIM + sg * 8;

    const int dofs0 = wv * 512;
    const int dofs1 = 4096 + wv * 512;

    f32x4 acc[8][4];
    const f32x4 zero = {0.0f, 0.0f, 0.0f, 0.0f};
    #pragma unroll
    for (int i = 0; i < 8; ++i)
        #pragma unroll
        for (int j = 0; j < 4; ++j) acc[i][j] = zero;

    // prologue: stage tiles 0 and 1
    async_cp16(gA0,      &sA[0][dofs0]);
    async_cp16(gB0,      &sB[0][dofs0]);
    async_cp16(gA1,      &sA[0][dofs1]);
    async_cp16(gB1,      &sB[0][dofs1]);
    async_cp16(gA0 + 32, &sA[1][dofs0]);
    async_cp16(gB0 + 32, &sB[1][dofs0]);
    async_cp16(gA1 + 32, &sA[1][dofs1]);
    async_cp16(gB1 + 32, &sB[1][dofs1]);
    asm volatile("s_waitcnt vmcnt(4)" ::: "memory");
    __builtin_amdgcn_s_barrier();
    __builtin_amdgcn_sched_barrier(0);

    const int NT = I_DIM / 32;   // 128
    for (int t = 0; t < NT; ++t) {
        const int cur = t % 3;
        const int nx2 = (t + 2) % 3;
        const bool stg = (t + 2) < NT;
        const int kt2 = (t + 2) * 32;

        // ---- phase A: m-frags 0..3 ----
        bf16x8 af[4], bfr[4];
        #pragma unroll
        for (int i = 0; i < 4; ++i) af[i] = *(const bf16x8*)(&sA[cur][aoff + i * 512]);
        #pragma unroll
        for (int j = 0; j < 4; ++j) bfr[j] = *(const bf16x8*)(&sB[cur][boff + j * 512]);
        if (stg) {
            async_cp16(gA0 + kt2, &sA[nx2][dofs0]);
            async_cp16(gB0 + kt2, &sB[nx2][dofs0]);
        }
        __builtin_amdgcn_s_barrier();
        __builtin_amdgcn_s_setprio(1);
        #pragma unroll
        for (int i = 0; i < 4; ++i)
            #pragma unroll
            for (int j = 0; j < 4; ++j)
                acc[i][j] = __builtin_amdgcn_mfma_f32_16x16x32_bf16(af[i], bfr[j], acc[i][j], 0, 0, 0);
        __builtin_amdgcn_s_setprio(0);
        __builtin_amdgcn_s_barrier();

        // ---- phase B: m-frags 4..7 (reuses bfr) ----
        bf16x8 af2[4];
        #pragma unroll
        for (int i = 0; i < 4; ++i) af2[i] = *(const bf16x8*)(&sA[cur][aoff + (i + 4) * 512]);
        if (stg) {
            async_cp16(gA1 + kt2, &sA[nx2][dofs1]);
            async_cp16(gB1 + kt2, &sB[nx2][dofs1]);
        }
        __builtin_amdgcn_s_barrier();
        __builtin_amdgcn_s_setprio(1);
        #pragma unroll
        for (int i = 0; i < 4; ++i)
            #pragma unroll
            for (int j = 0; j < 4; ++j)
                acc[i + 4][j] = __builtin_amdgcn_mfma_f32_16x16x32_bf16(af2[i], bfr[j], acc[i + 4][j], 0, 0, 0);
        __builtin_amdgcn_s_setprio(0);

        if (t + 1 < NT) {
            if (stg) asm volatile("s_waitcnt vmcnt(4)" ::: "memory");
            else     asm volatile("s_waitcnt vmcnt(0)" ::: "memory");
            __builtin_amdgcn_s_barrier();
            __builtin_amdgcn_sched_barrier(0);
        }
    }

    #pragma unroll
    for (int i = 0; i < 8; ++i) {
        #pragma unroll
        for (int r = 0; r < 4; ++r) {
            int mloc = wm + i * 16 + q * 4 + r;
            int slot = mt * 256 + mloc;
            if (slot < ne) {
                float* obase = ybuf + (size_t)(off + slot) * H_DIM + nt * 256 + wn;
                #pragma unroll
                for (int j = 0; j < 4; ++j)
                    obase[j * 16 + c] = acc[i][j][r];
            }
        }
    }
}

// combine: out[t] = w0 * y[slot0] + w1 * y[slot1]
__global__ void combine_kernel(const float* __restrict__ ybuf,
                               const float* __restrict__ bw,
                               const int* __restrict__ tok2slot,
                               float* __restrict__ out) {
    int i = blockIdx.x * blockDim.x + threadIdx.x;   // over float4 of out
    int t = i >> 9;            // H/4 = 512
    int h4 = i & 511;
    int p0 = tok2slot[2 * t], p1 = tok2slot[2 * t + 1];
    float w0 = bw[p0], w1 = bw[p1];
    float4 a = ((const float4*)(ybuf + (size_t)p0 * H_DIM))[h4];
    float4 b = ((const float4*)(ybuf + (size_t)p1 * H_DIM))[h4];
    float4 o;
    o.x = w0 * a.x + w1 * b.x;
    o.y = w0 * a.y + w1 * b.y;
    o.z = w0 * a.z + w1 * b.z;
    o.w = w0 * a.w + w1 * b.w;
    ((float4*)(out + (size_t)t * H_DIM))[h4] = o;
}

// =====================  PATH B: fallback (fp32 weights in-loop) ==============

__global__ __launch_bounds__(256, 2)
void gemm1_kernel(const unsigned short* __restrict__ Xb,
                  const float* __restrict__ W1,
                  const float* __restrict__ W3,
                  const int* __restrict__ counts,
                  const int* __restrict__ offsets,
                  const int* __restrict__ btok,
                  unsigned short* __restrict__ hbuf) {
    const int e = blockIdx.z;
    const int ne = counts[e];
    const int mt = blockIdx.y;
    if (mt * 128 >= ne) return;
    const int nt = blockIdx.x;
    const int off = offsets[e];

    __shared__ unsigned short sA[128][32];
    __shared__ unsigned short sB1[128][32];
    __shared__ unsigned short sB3[128][32];
    __shared__ int s_tok[128];

    const int tid = threadIdx.x;
    if (tid < 128) {
        int slot = mt * 128 + tid;
        s_tok[tid] = (slot < ne) ? btok[off + slot] : -1;
    }

    const float* __restrict__ pB1 = W1 + (size_t)e * I_DIM * H_DIM + (size_t)(nt * 128) * H_DIM;
    const float* __restrict__ pB3 = W3 + (size_t)e * I_DIM * H_DIM + (size_t)(nt * 128) * H_DIM;

    const int lane = tid & 63;
    const int wv = tid >> 6;
    const int wm = (wv >> 1) << 6;
    const int wn = (wv & 1) << 6;
    const int q = lane >> 4;
    const int c = lane & 15;

    f32x4 accg[4][4], accu[4][4];
    const f32x4 zero = {0.0f, 0.0f, 0.0f, 0.0f};
    #pragma unroll
    for (int i = 0; i < 4; ++i)
        #pragma unroll
        for (int j = 0; j < 4; ++j) { accg[i][j] = zero; accu[i][j] = zero; }

    const int srow = tid >> 2;
    const int schunk = (tid & 3) * 8;

    for (int kt = 0; kt < H_DIM; kt += 32) {
        __syncthreads();
        #pragma unroll
        for (int p = 0; p < 2; ++p) {
            int r = srow + p * 64;
            int tok = s_tok[r];
            u16x8 av = {0, 0, 0, 0, 0, 0, 0, 0};
            if (tok >= 0)
                av = *(const u16x8*)(Xb + (size_t)tok * H_DIM + kt + schunk);
            *(u16x8*)(&sA[r][schunk]) = av;

            const float* b1 = pB1 + (size_t)r * H_DIM + kt + schunk;
            float4 x0 = *(const float4*)(b1);
            float4 x1 = *(const float4*)(b1 + 4);
            u16x8 bv;
            bv[0] = f2bf(x0.x); bv[1] = f2bf(x0.y); bv[2] = f2bf(x0.z); bv[3] = f2bf(x0.w);
            bv[4] = f2bf(x1.x); bv[5] = f2bf(x1.y); bv[6] = f2bf(x1.z); bv[7] = f2bf(x1.w);
            *(u16x8*)(&sB1[r][schunk]) = bv;

            const float* b3 = pB3 + (size_t)r * H_DIM + kt + schunk;
            float4 y0 = *(const float4*)(b3);
            float4 y1 = *(const float4*)(b3 + 4);
            u16x8 cv;
            cv[0] = f2bf(y0.x); cv[1] = f2bf(y0.y); cv[2] = f2bf(y0.z); cv[3] = f2bf(y0.w);
            cv[4] = f2bf(y1.x); cv[5] = f2bf(y1.y); cv[6] = f2bf(y1.z); cv[7] = f2bf(y1.w);
            *(u16x8*)(&sB3[r][schunk]) = cv;
        }
        __syncthreads();

        bf16x8 af[4], b1f[4], b3f[4];
        #pragma unroll
        for (int i = 0; i < 4; ++i)
            af[i] = *(const bf16x8*)(&sA[wm + i * 16 + c][q * 8]);
        #pragma unroll
        for (int j = 0; j < 4; ++j) {
            b1f[j] = *(const bf16x8*)(&sB1[wn + j * 16 + c][q * 8]);
            b3f[j] = *(const bf16x8*)(&sB3[wn + j * 16 + c][q * 8]);
        }
        #pragma unroll
        for (int i = 0; i < 4; ++i)
            #pragma unroll
            for (int j = 0; j < 4; ++j) {
                accg[i][j] = __builtin_amdgcn_mfma_f32_16x16x32_bf16(af[i], b1f[j], accg[i][j], 0, 0, 0);
                accu[i][j] = __builtin_amdgcn_mfma_f32_16x16x32_bf16(af[i], b3f[j], accu[i][j], 0, 0, 0);
            }
    }

    #pragma unroll
    for (int i = 0; i < 4; ++i) {
        #pragma unroll
        for (int r = 0; r < 4; ++r) {
            int mloc = wm + i * 16 + q * 4 + r;
            int slot = mt * 128 + mloc;
            if (slot < ne) {
                size_t rowbase = (size_t)(off + slot) * I_DIM + nt * 128 + wn;
                #pragma unroll
                for (int j = 0; j < 4; ++j) {
                    float g = accg[i][j][r];
                    float u = accu[i][j][r];
                    float val = (g / (1.0f + __expf(-g))) * u;
                    hbuf[rowbase + j * 16 + c] = f2bf(val);
                }
            }
        }
    }
}

__global__ __launch_bounds__(256, 2)
void gemm2_kernel(const unsigned short* __restrict__ hbuf,
                  const float* __restrict__ W2,
                  const int* __restrict__ counts,
                  const int* __restrict__ offsets,
                  const int* __restrict__ btok,
                  const float* __restrict__ bw,
                  float* __restrict__ out) {
    const int e = blockIdx.z;
    const int ne = counts[e];
    const int mt = blockIdx.y;
    if (mt * 128 >= ne) return;
    const int nt = blockIdx.x;
    const int off = offsets[e];

    __shared__ unsigned short sA[128][32];
    __shared__ unsigned short sB[128][32];

    const int tid = threadIdx.x;
    const int lane = tid & 63;
    const int wv = tid >> 6;
    const int wm = (wv >> 1) << 6;
    const int wn = (wv & 1) << 6;
    const int q = lane >> 4;
    const int c = lane & 15;

    const float* __restrict__ pB = W2 + (size_t)e * H_DIM * I_DIM + (size_t)(nt * 128) * I_DIM;

    f32x4 acc[4][4];
    const f32x4 zero = {0.0f, 0.0f, 0.0f, 0.0f};
    #pragma unroll
    for (int i = 0; i < 4; ++i)
        #pragma unroll
        for (int j = 0; j < 4; ++j) acc[i][j] = zero;

    const int srow = tid >> 2;
    const int schunk = (tid & 3) * 8;

    for (int kt = 0; kt < I_DIM; kt += 32) {
        __syncthreads();
        #pragma unroll
        for (int p = 0; p < 2; ++p) {
            int r = srow + p * 64;
            int slot = mt * 128 + r;
            u16x8 av = {0, 0, 0, 0, 0, 0, 0, 0};
            if (slot < ne)
                av = *(const u16x8*)(hbuf + (size_t)(off + slot) * I_DIM + kt + schunk);
            *(u16x8*)(&sA[r][schunk]) = av;

            const float* b = pB + (size_t)r * I_DIM + kt + schunk;
            float4 x0 = *(const float4*)(b);
            float4 x1 = *(const float4*)(b + 4);
            u16x8 bv;
            bv[0] = f2bf(x0.x); bv[1] = f2bf(x0.y); bv[2] = f2bf(x0.z); bv[3] = f2bf(x0.w);
            bv[4] = f2bf(x1.x); bv[5] = f2bf(x1.y); bv[6] = f2bf(x1.z); bv[7] = f2bf(x1.w);
            *(u16x8*)(&sB[r][schunk]) = bv;
        }
        __syncthreads();

        bf16x8 af[4], bfr[4];
        #pragma unroll
        for (int i = 0; i < 4; ++i)
            af[i] = *(const bf16x8*)(&sA[wm + i * 16 + c][q * 8]);
        #pragma unroll
        for (int j = 0; j < 4; ++j)
            bfr[j] = *(const bf16x8*)(&sB[wn + j * 16 + c][q * 8]);
        #pragma unroll
        for (int i = 0; i < 4; ++i)
            #pragma unroll
            for (int j = 0; j < 4; ++j)
                acc[i][j] = __builtin_amdgcn_mfma_f32_16x16x32_bf16(af[i], bfr[j], acc[i][j], 0, 0, 0);
    }

    #pragma unroll
    for (int i = 0; i < 4; ++i) {
        #pragma unroll
        for (int r = 0; r < 4; ++r) {
            int mloc = wm + i * 16 + q * 4 + r;
            int slot = mt * 128 + mloc;
            if (slot < ne) {
                int tok = btok[off + slot];
                float wgt = bw[off + slot];
                float* obase = out + (size_t)tok * H_DIM + nt * 128 + wn;
                #pragma unroll
                for (int j = 0; j < 4; ++j)
                    atomicAdd(obase + j * 16 + c, wgt * acc[i][j][r]);
            }
        }
    }
}

// ============================================================================

extern "C" void kernel_launch(void* const* d_in, const int* in_sizes, int n_in,
                              void* d_out, int out_size, void* d_ws, size_t ws_size,
                              hipStream_t stream) {
    const float* hs = (const float*)d_in[0];   // [T, H]
    const float* rl = (const float*)d_in[1];   // [T, E]
    const float* w1 = (const float*)d_in[2];   // [E, I, H]
    const float* w3 = (const float*)d_in[3];   // [E, I, H]
    const float* w2 = (const float*)d_in[4];   // [E, H, I]
    float* out = (float*)d_out;

    char* ws = (char*)d_ws;
    // meta region (first 1 MB)
    int*   counts   = (int*)(ws);
    int*   offsets  = (int*)(ws + 256);
    int*   btok     = (int*)(ws + 4096);            // 8192 ints
    float* bw       = (float*)(ws + 36864);         // 8192 floats
    int*   tok2slot = (int*)(ws + 69632);           // 8192 ints

    const size_t MB = 1ull << 20;
    const size_t NEED_A = 529 * MB;

    if (ws_size >= NEED_A) {
        // -------- Path A: preconvert weights to bf16, pipelined GEMMs -------
        unsigned short* Xb   = (unsigned short*)(ws + 1 * MB);     // 16 MB
        unsigned short* hbuf = (unsigned short*)(ws + 17 * MB);    // 64 MB
        float*          ybuf = (float*)(ws + 81 * MB);             // 64 MB
        unsigned short* w1b  = (unsigned short*)(ws + 145 * MB);   // 128 MB
        unsigned short* w3b  = (unsigned short*)(ws + 273 * MB);   // 128 MB
        unsigned short* w2b  = (unsigned short*)(ws + 401 * MB);   // 128 MB

        routing_kernel<<<1, 256, 0, stream>>>(rl, counts, offsets, btok, bw, tok2slot);

        cvt_kernel<<<(T_TOK * H_DIM / 4) / 256, 256, 0, stream>>>(hs, Xb);
        int wn4 = N_EXP * I_DIM * H_DIM / 4;   // 16M float4 per weight tensor
        cvt_kernel<<<wn4 / 256, 256, 0, stream>>>(w1, w1b);
        cvt_kernel<<<wn4 / 256, 256, 0, stream>>>(w3, w3b);
        cvt_kernel<<<wn4 / 256, 256, 0, stream>>>(w2, w2b);

        gemm1p_kernel<<<dim3(I_DIM / 128, 32, N_EXP), 512, 0, stream>>>(
            Xb, w1b, w3b, counts, offsets, btok, hbuf);

        gemm2p_kernel<<<dim3(H_DIM / 256, 32, N_EXP), 512, 0, stream>>>(
            hbuf, w2b, counts, offsets, ybuf);

        combine_kernel<<<(T_TOK * (H_DIM / 4)) / 256, 256, 0, stream>>>(
            ybuf, bw, tok2slot, out);
    } else {
        // -------- Path B: fallback (known-good round-1 structure) -----------
        unsigned short* Xb   = (unsigned short*)(ws + 1 * MB);            // 16 MB
        unsigned short* hbuf = (unsigned short*)(ws + 32 * MB);           // 64 MB

        hipMemsetAsync(out, 0, (size_t)T_TOK * H_DIM * sizeof(float), stream);

        routing_kernel<<<1, 256, 0, stream>>>(rl, counts, offsets, btok, bw, tok2slot);

        cvt_kernel<<<(T_TOK * H_DIM / 4) / 256, 256, 0, stream>>>(hs, Xb);

        gemm1_kernel<<<dim3(I_DIM / 128, T_TOK / 128, N_EXP), 256, 0, stream>>>(
            Xb, w1, w3, counts, offsets, btok, hbuf);

        gemm2_kernel<<<dim3(H_DIM / 128, T_TOK / 128, N_EXP), 256, 0, stream>>>(
            hbuf, w2, counts, offsets, btok, bw, out);
    }
}

// Round 2
// 1249.421 us; speedup vs baseline: 1.0956x; 1.0212x over previous
//
#include <hip/hip_runtime.h>
#include <stdint.h>

#define T_TOK 4096
#define H_DIM 2048
#define I_DIM 4096
#define N_EXP 8

typedef __attribute__((ext_vector_type(8))) short bf16x8;     // MFMA A/B frag (8 bf16)
typedef __attribute__((ext_vector_type(4))) float f32x4;      // MFMA C/D frag
typedef __attribute__((ext_vector_type(8))) unsigned short u16x8;

__device__ __forceinline__ unsigned short f2bf(float x) {
    union { float f; unsigned u; } v; v.f = x;
    unsigned r = v.u + 0x7FFF + ((v.u >> 16) & 1);   // RNE
    return (unsigned short)(r >> 16);
}

// Direct global->LDS async copy, 16B per lane. LDS dest = wave-uniform base + lane*16.
__device__ __forceinline__ void async_cp16(const void* g, const unsigned short* lds_base) {
    __builtin_amdgcn_global_load_lds(
        (const __attribute__((address_space(1))) unsigned*)g,
        (__attribute__((address_space(3))) unsigned*)(unsigned)(uintptr_t)lds_base,
        16, 0, 0);
}

// ---------------- routing: top-2 + softmax + bucketize (single block) ----------
__global__ void routing_kernel(const float* __restrict__ logits,
                               int* __restrict__ counts, int* __restrict__ offsets,
                               int* __restrict__ btok, float* __restrict__ bw,
                               int* __restrict__ tok2slot) {
    __shared__ int s_cnt[N_EXP];
    __shared__ int s_off[N_EXP];
    __shared__ int s_cur[N_EXP];
    const int tid = threadIdx.x;   // 256 threads, 16 tokens each
    if (tid < N_EXP) s_cnt[tid] = 0;
    __syncthreads();

    int e0a[16], e1a[16]; float w0a[16], w1a[16];
    #pragma unroll
    for (int it = 0; it < 16; ++it) {
        int t = tid + it * 256;
        float l[8];
        #pragma unroll
        for (int e = 0; e < 8; ++e) l[e] = logits[t * 8 + e];
        int b0 = 0; float v0 = l[0];
        #pragma unroll
        for (int e = 1; e < 8; ++e) if (l[e] > v0) { v0 = l[e]; b0 = e; }
        int b1 = (b0 == 0) ? 1 : 0; float v1 = l[b1];
        #pragma unroll
        for (int e = 0; e < 8; ++e) if (e != b0 && l[e] > v1) { v1 = l[e]; b1 = e; }
        float w0 = 1.0f / (1.0f + __expf(v1 - v0));
        e0a[it] = b0; e1a[it] = b1; w0a[it] = w0; w1a[it] = 1.0f - w0;
        atomicAdd(&s_cnt[b0], 1);
        atomicAdd(&s_cnt[b1], 1);
    }
    __syncthreads();
    if (tid == 0) {
        int acc = 0;
        for (int e = 0; e < N_EXP; ++e) { s_off[e] = acc; s_cur[e] = acc; acc += s_cnt[e]; }
    }
    __syncthreads();
    if (tid < N_EXP) { counts[tid] = s_cnt[tid]; offsets[tid] = s_off[tid]; }
    #pragma unroll
    for (int it = 0; it < 16; ++it) {
        int t = tid + it * 256;
        int p0 = atomicAdd(&s_cur[e0a[it]], 1);
        btok[p0] = t; bw[p0] = w0a[it];
        int p1 = atomicAdd(&s_cur[e1a[it]], 1);
        btok[p1] = t; bw[p1] = w1a[it];
        tok2slot[2 * t] = p0;
        tok2slot[2 * t + 1] = p1;
    }
}

// ---------------- fp32 -> bf16 convert (generic) -----------------------------
__global__ void cvt_kernel(const float* __restrict__ x, unsigned short* __restrict__ xb) {
    int i = blockIdx.x * blockDim.x + threadIdx.x;   // over float4s
    float4 v = ((const float4*)x)[i];
    ushort4 o;
    o.x = f2bf(v.x); o.y = f2bf(v.y); o.z = f2bf(v.z); o.w = f2bf(v.w);
    ((ushort4*)xb)[i] = o;
}

// =====================  PATH A: pipelined bf16 GEMMs =========================
//
// Ring-4 K-half pipeline (T3+T4+T5), ONE barrier + ONE counted vmcnt per phase:
//   phase h: {ds_read 12 frags from slot h&3 | stage half h+3 into (h+3)&3
//             | setprio(1) 32xMFMA setprio(0) | vmcnt(8) | s_barrier}
// Hazards:
//   - stage (h+3)&3 == (h-1)&3 vs readers of h-1: every wave's lgkmcnt(0)
//     (compiler-inserted before MFMA use) precedes the phase-(h-1) barrier,
//     and gload LDS-writes occur strictly after issue => safe.
//   - read slot h: its 4 loads were issued at phase h-3; vmcnt(8) at the end
//     of phase h-1 keeps only the 8 newest (h+1,h+2) in flight => h landed.
// Tail: vmcnt(4) then vmcnt(0) for the last two boundaries only.
// Swizzle (verified, conflicts=0): source chunk (lane&3)^((lane>>3)&3) with
// linear LDS dest; reads at slot q^((c>>1)&3).

// GEMM1: h[slot,i] = silu(x@W1^T) * (x@W3^T).  BM=256 x BN=128(+128), K=H_DIM.
__global__ __launch_bounds__(512, 2)
void gemm1p_kernel(const unsigned short* __restrict__ Xb,
                   const unsigned short* __restrict__ W1b,
                   const unsigned short* __restrict__ W3b,
                   const int* __restrict__ counts,
                   const int* __restrict__ offsets,
                   const int* __restrict__ btok,
                   unsigned short* __restrict__ hbuf) {
    const int e = blockIdx.z;
    const int ne = counts[e];
    const int mt = blockIdx.y;
    if (mt * 256 >= ne) return;
    const int nt = blockIdx.x;
    const int off = offsets[e];

    __shared__ unsigned short sA[4][256 * 32];    // 64 KB  (ring of K-halves)
    __shared__ unsigned short sB1[4][128 * 32];   // 32 KB
    __shared__ unsigned short sB3[4][128 * 32];   // 32 KB  -> exactly 128 KB

    const int tid = threadIdx.x;
    const int lane = tid & 63;
    const int wv = tid >> 6;
    const int wm = (wv >> 1) << 6;   // 4 M-waves of 64
    const int wn = (wv & 1) << 6;    // 2 N-waves of 64
    const int q = lane >> 4;
    const int c = lane & 15;
    const int xq = q ^ ((c >> 1) & 3);          // swizzled read slot

    const int aoff = (wm + c) * 32 + xq * 8;
    const int boff = (wn + c) * 32 + xq * 8;

    // staging: wave wv stages rows wv*16..wv*16+15 per 128-row group
    const int srow = wv * 16 + (lane >> 2);           // 0..127
    const int sg = (lane & 3) ^ ((lane >> 3) & 3);    // pre-swizzled source chunk

    int sl0 = mt * 256 + srow;        if (sl0 >= ne) sl0 = ne - 1;
    int sl1 = mt * 256 + srow + 128;  if (sl1 >= ne) sl1 = ne - 1;
    const int tok0 = btok[off + sl0];
    const int tok1 = btok[off + sl1];

    const unsigned short* gA0 = Xb + (size_t)tok0 * H_DIM + sg * 8;
    const unsigned short* gA1 = Xb + (size_t)tok1 * H_DIM + sg * 8;
    const size_t wrow = (size_t)e * I_DIM + nt * 128 + srow;
    const unsigned short* gB1 = W1b + wrow * H_DIM + sg * 8;
    const unsigned short* gB3 = W3b + wrow * H_DIM + sg * 8;

    const int dofsA0 = wv * 512;            // LDS element offsets (wave-uniform)
    const int dofsA1 = 4096 + wv * 512;
    const int dofsB  = wv * 512;

    f32x4 accg[4][4], accu[4][4];
    const f32x4 zero = {0.0f, 0.0f, 0.0f, 0.0f};
    #pragma unroll
    for (int i = 0; i < 4; ++i)
        #pragma unroll
        for (int j = 0; j < 4; ++j) { accg[i][j] = zero; accu[i][j] = zero; }

    // prologue: stage halves 0,1,2 (4 loads each, in half order for vmcnt math)
    #pragma unroll
    for (int h = 0; h < 3; ++h) {
        const int k = h * 32;
        async_cp16(gA0 + k, &sA[h][dofsA0]);
        async_cp16(gA1 + k, &sA[h][dofsA1]);
        async_cp16(gB1 + k, &sB1[h][dofsB]);
        async_cp16(gB3 + k, &sB3[h][dofsB]);
    }
    asm volatile("s_waitcnt vmcnt(8)" ::: "memory");   // half 0 landed
    __builtin_amdgcn_s_barrier();
    __builtin_amdgcn_sched_barrier(0);

    const int NT = H_DIM / 32;   // 64
    #pragma unroll 4
    for (int h = 0; h < NT; ++h) {
        const unsigned short* pA  = sA[h & 3];
        const unsigned short* pB1 = sB1[h & 3];
        const unsigned short* pB3 = sB3[h & 3];

        bf16x8 af[4], b1f[4], b3f[4];
        #pragma unroll
        for (int i = 0; i < 4; ++i) af[i]  = *(const bf16x8*)(pA  + aoff + i * 512);
        #pragma unroll
        for (int j = 0; j < 4; ++j) b1f[j] = *(const bf16x8*)(pB1 + boff + j * 512);
        #pragma unroll
        for (int j = 0; j < 4; ++j) b3f[j] = *(const bf16x8*)(pB3 + boff + j * 512);

        if (h + 3 < NT) {
            const int r3 = (h + 3) & 3;
            const int k3 = (h + 3) * 32;
            async_cp16(gA0 + k3, &sA[r3][dofsA0]);
            async_cp16(gA1 + k3, &sA[r3][dofsA1]);
            async_cp16(gB1 + k3, &sB1[r3][dofsB]);
            async_cp16(gB3 + k3, &sB3[r3][dofsB]);
        }

        __builtin_amdgcn_s_setprio(1);
        #pragma unroll
        for (int i = 0; i < 4; ++i)
            #pragma unroll
            for (int j = 0; j < 4; ++j)
                accg[i][j] = __builtin_amdgcn_mfma_f32_16x16x32_bf16(af[i], b1f[j], accg[i][j], 0, 0, 0);
        #pragma unroll
        for (int i = 0; i < 4; ++i)
            #pragma unroll
            for (int j = 0; j < 4; ++j)
                accu[i][j] = __builtin_amdgcn_mfma_f32_16x16x32_bf16(af[i], b3f[j], accu[i][j], 0, 0, 0);
        __builtin_amdgcn_s_setprio(0);

        if (h + 1 < NT) {
            if (h + 3 < NT)      asm volatile("s_waitcnt vmcnt(8)" ::: "memory");
            else if (h + 2 < NT) asm volatile("s_waitcnt vmcnt(4)" ::: "memory");
            else                 asm volatile("s_waitcnt vmcnt(0)" ::: "memory");
            __builtin_amdgcn_s_barrier();
            __builtin_amdgcn_sched_barrier(0);
        }
    }

    // epilogue: silu(gate)*up -> bf16
    #pragma unroll
    for (int i = 0; i < 4; ++i) {
        #pragma unroll
        for (int r = 0; r < 4; ++r) {
            int mloc = wm + i * 16 + q * 4 + r;
            int slot = mt * 256 + mloc;
            if (slot < ne) {
                size_t rowbase = (size_t)(off + slot) * I_DIM + nt * 128 + wn;
                #pragma unroll
                for (int j = 0; j < 4; ++j) {
                    float g = accg[i][j][r];
                    float u = accu[i][j][r];
                    float val = (g / (1.0f + __expf(-g))) * u;
                    hbuf[rowbase + j * 16 + c] = f2bf(val);
                }
            }
        }
    }
}

// GEMM2: y[slot,h] = h[slot] @ W2^T.  BM=256 x BN=128, K=I_DIM. Ring-4, 96 KB.
__global__ __launch_bounds__(512, 2)
void gemm2p_kernel(const unsigned short* __restrict__ hbuf,
                   const unsigned short* __restrict__ W2b,
                   const int* __restrict__ counts,
                   const int* __restrict__ offsets,
                   float* __restrict__ ybuf) {
    const int e = blockIdx.z;
    const int ne = counts[e];
    const int mt = blockIdx.y;
    if (mt * 256 >= ne) return;
    const int nt = blockIdx.x;
    const int off = offsets[e];

    __shared__ unsigned short sA[4][256 * 32];   // 64 KB
    __shared__ unsigned short sB[4][128 * 32];   // 32 KB

    const int tid = threadIdx.x;
    const int lane = tid & 63;
    const int wv = tid >> 6;
    const int wm = (wv >> 1) << 6;   // 4 M-waves of 64
    const int wn = (wv & 1) << 6;    // 2 N-waves of 64
    const int q = lane >> 4;
    const int c = lane & 15;
    const int xq = q ^ ((c >> 1) & 3);

    const int aoff = (wm + c) * 32 + xq * 8;
    const int boff = (wn + c) * 32 + xq * 8;

    const int srow = wv * 16 + (lane >> 2);
    const int sg = (lane & 3) ^ ((lane >> 3) & 3);

    int slot0 = mt * 256 + srow;        if (slot0 >= ne) slot0 = ne - 1;
    int slot1 = mt * 256 + srow + 128;  if (slot1 >= ne) slot1 = ne - 1;
    const unsigned short* gA0 = hbuf + (size_t)(off + slot0) * I_DIM + sg * 8;
    const unsigned short* gA1 = hbuf + (size_t)(off + slot1) * I_DIM + sg * 8;
    const size_t wrow = (size_t)e * H_DIM + nt * 128 + srow;
    const unsigned short* gB = W2b + wrow * I_DIM + sg * 8;

    const int dofsA0 = wv * 512;
    const int dofsA1 = 4096 + wv * 512;
    const int dofsB  = wv * 512;

    f32x4 acc[4][4];
    const f32x4 zero = {0.0f, 0.0f, 0.0f, 0.0f};
    #pragma unroll
    for (int i = 0; i < 4; ++i)
        #pragma unroll
        for (int j = 0; j < 4; ++j) acc[i][j] = zero;

    // prologue: stage halves 0,1,2 (3 loads each)
    #pragma unroll
    for (int h = 0; h < 3; ++h) {
        const int k = h * 32;
        async_cp16(gA0 + k, &sA[h][dofsA0]);
        async_cp16(gA1 + k, &sA[h][dofsA1]);
        async_cp16(gB + k,  &sB[h][dofsB]);
    }
    asm volatile("s_waitcnt vmcnt(6)" ::: "memory");   // half 0 landed
    __builtin_amdgcn_s_barrier();
    __builtin_amdgcn_sched_barrier(0);

    const int NT = I_DIM / 32;   // 128
    #pragma unroll 4
    for (int h = 0; h < NT; ++h) {
        const unsigned short* pA = sA[h & 3];
        const unsigned short* pB = sB[h & 3];

        bf16x8 af[4], bfr[4];
        #pragma unroll
        for (int i = 0; i < 4; ++i) af[i]  = *(const bf16x8*)(pA + aoff + i * 512);
        #pragma unroll
        for (int j = 0; j < 4; ++j) bfr[j] = *(const bf16x8*)(pB + boff + j * 512);

        if (h + 3 < NT) {
            const int r3 = (h + 3) & 3;
            const int k3 = (h + 3) * 32;
            async_cp16(gA0 + k3, &sA[r3][dofsA0]);
            async_cp16(gA1 + k3, &sA[r3][dofsA1]);
            async_cp16(gB + k3,  &sB[r3][dofsB]);
        }

        __builtin_amdgcn_s_setprio(1);
        #pragma unroll
        for (int i = 0; i < 4; ++i)
            #pragma unroll
            for (int j = 0; j < 4; ++j)
                acc[i][j] = __builtin_amdgcn_mfma_f32_16x16x32_bf16(af[i], bfr[j], acc[i][j], 0, 0, 0);
        __builtin_amdgcn_s_setprio(0);

        if (h + 1 < NT) {
            if (h + 3 < NT)      asm volatile("s_waitcnt vmcnt(6)" ::: "memory");
            else if (h + 2 < NT) asm volatile("s_waitcnt vmcnt(3)" ::: "memory");
            else                 asm volatile("s_waitcnt vmcnt(0)" ::: "memory");
            __builtin_amdgcn_s_barrier();
            __builtin_amdgcn_sched_barrier(0);
        }
    }

    #pragma unroll
    for (int i = 0; i < 4; ++i) {
        #pragma unroll
        for (int r = 0; r < 4; ++r) {
            int mloc = wm + i * 16 + q * 4 + r;
            int slot = mt * 256 + mloc;
            if (slot < ne) {
                float* obase = ybuf + (size_t)(off + slot) * H_DIM + nt * 128 + wn;
                #pragma unroll
                for (int j = 0; j < 4; ++j)
                    obase[j * 16 + c] = acc[i][j][r];
            }
        }
    }
}

// combine: out[t] = w0 * y[slot0] + w1 * y[slot1]
__global__ void combine_kernel(const float* __restrict__ ybuf,
                               const float* __restrict__ bw,
                               const int* __restrict__ tok2slot,
                               float* __restrict__ out) {
    int i = blockIdx.x * blockDim.x + threadIdx.x;   // over float4 of out
    int t = i >> 9;            // H/4 = 512
    int h4 = i & 511;
    int p0 = tok2slot[2 * t], p1 = tok2slot[2 * t + 1];
    float w0 = bw[p0], w1 = bw[p1];
    float4 a = ((const float4*)(ybuf + (size_t)p0 * H_DIM))[h4];
    float4 b = ((const float4*)(ybuf + (size_t)p1 * H_DIM))[h4];
    float4 o;
    o.x = w0 * a.x + w1 * b.x;
    o.y = w0 * a.y + w1 * b.y;
    o.z = w0 * a.z + w1 * b.z;
    o.w = w0 * a.w + w1 * b.w;
    ((float4*)(out + (size_t)t * H_DIM))[h4] = o;
}

// =====================  PATH B: fallback (fp32 weights in-loop) ==============

__global__ __launch_bounds__(256, 2)
void gemm1_kernel(const unsigned short* __restrict__ Xb,
                  const float* __restrict__ W1,
                  const float* __restrict__ W3,
                  const int* __restrict__ counts,
                  const int* __restrict__ offsets,
                  const int* __restrict__ btok,
                  unsigned short* __restrict__ hbuf) {
    const int e = blockIdx.z;
    const int ne = counts[e];
    const int mt = blockIdx.y;
    if (mt * 128 >= ne) return;
    const int nt = blockIdx.x;
    const int off = offsets[e];

    __shared__ unsigned short sA[128][32];
    __shared__ unsigned short sB1[128][32];
    __shared__ unsigned short sB3[128][32];
    __shared__ int s_tok[128];

    const int tid = threadIdx.x;
    if (tid < 128) {
        int slot = mt * 128 + tid;
        s_tok[tid] = (slot < ne) ? btok[off + slot] : -1;
    }

    const float* __restrict__ pB1 = W1 + (size_t)e * I_DIM * H_DIM + (size_t)(nt * 128) * H_DIM;
    const float* __restrict__ pB3 = W3 + (size_t)e * I_DIM * H_DIM + (size_t)(nt * 128) * H_DIM;

    const int lane = tid & 63;
    const int wv = tid >> 6;
    const int wm = (wv >> 1) << 6;
    const int wn = (wv & 1) << 6;
    const int q = lane >> 4;
    const int c = lane & 15;

    f32x4 accg[4][4], accu[4][4];
    const f32x4 zero = {0.0f, 0.0f, 0.0f, 0.0f};
    #pragma unroll
    for (int i = 0; i < 4; ++i)
        #pragma unroll
        for (int j = 0; j < 4; ++j) { accg[i][j] = zero; accu[i][j] = zero; }

    const int srow = tid >> 2;
    const int schunk = (tid & 3) * 8;

    for (int kt = 0; kt < H_DIM; kt += 32) {
        __syncthreads();
        #pragma unroll
        for (int p = 0; p < 2; ++p) {
            int r = srow + p * 64;
            int tok = s_tok[r];
            u16x8 av = {0, 0, 0, 0, 0, 0, 0, 0};
            if (tok >= 0)
                av = *(const u16x8*)(Xb + (size_t)tok * H_DIM + kt + schunk);
            *(u16x8*)(&sA[r][schunk]) = av;

            const float* b1 = pB1 + (size_t)r * H_DIM + kt + schunk;
            float4 x0 = *(const float4*)(b1);
            float4 x1 = *(const float4*)(b1 + 4);
            u16x8 bv;
            bv[0] = f2bf(x0.x); bv[1] = f2bf(x0.y); bv[2] = f2bf(x0.z); bv[3] = f2bf(x0.w);
            bv[4] = f2bf(x1.x); bv[5] = f2bf(x1.y); bv[6] = f2bf(x1.z); bv[7] = f2bf(x1.w);
            *(u16x8*)(&sB1[r][schunk]) = bv;

            const float* b3 = pB3 + (size_t)r * H_DIM + kt + schunk;
            float4 y0 = *(const float4*)(b3);
            float4 y1 = *(const float4*)(b3 + 4);
            u16x8 cv;
            cv[0] = f2bf(y0.x); cv[1] = f2bf(y0.y); cv[2] = f2bf(y0.z); cv[3] = f2bf(y0.w);
            cv[4] = f2bf(y1.x); cv[5] = f2bf(y1.y); cv[6] = f2bf(y1.z); cv[7] = f2bf(y1.w);
            *(u16x8*)(&sB3[r][schunk]) = cv;
        }
        __syncthreads();

        bf16x8 af[4], b1f[4], b3f[4];
        #pragma unroll
        for (int i = 0; i < 4; ++i)
            af[i] = *(const bf16x8*)(&sA[wm + i * 16 + c][q * 8]);
        #pragma unroll
        for (int j = 0; j < 4; ++j) {
            b1f[j] = *(const bf16x8*)(&sB1[wn + j * 16 + c][q * 8]);
            b3f[j] = *(const bf16x8*)(&sB3[wn + j * 16 + c][q * 8]);
        }
        #pragma unroll
        for (int i = 0; i < 4; ++i)
            #pragma unroll
            for (int j = 0; j < 4; ++j) {
                accg[i][j] = __builtin_amdgcn_mfma_f32_16x16x32_bf16(af[i], b1f[j], accg[i][j], 0, 0, 0);
                accu[i][j] = __builtin_amdgcn_mfma_f32_16x16x32_bf16(af[i], b3f[j], accu[i][j], 0, 0, 0);
            }
    }

    #pragma unroll
    for (int i = 0; i < 4; ++i) {
        #pragma unroll
        for (int r = 0; r < 4; ++r) {
            int mloc = wm + i * 16 + q * 4 + r;
            int slot = mt * 128 + mloc;
            if (slot < ne) {
                size_t rowbase = (size_t)(off + slot) * I_DIM + nt * 128 + wn;
                #pragma unroll
                for (int j = 0; j < 4; ++j) {
                    float g = accg[i][j][r];
                    float u = accu[i][j][r];
                    float val = (g / (1.0f + __expf(-g))) * u;
                    hbuf[rowbase + j * 16 + c] = f2bf(val);
                }
            }
        }
    }
}

__global__ __launch_bounds__(256, 2)
void gemm2_kernel(const unsigned short* __restrict__ hbuf,
                  const float* __restrict__ W2,
                  const int* __restrict__ counts,
                  const int* __restrict__ offsets,
                  const int* __restrict__ btok,
                  const float* __restrict__ bw,
                  float* __restrict__ out) {
    const int e = blockIdx.z;
    const int ne = counts[e];
    const int mt = blockIdx.y;
    if (mt * 128 >= ne) return;
    const int nt = blockIdx.x;
    const int off = offsets[e];

    __shared__ unsigned short sA[128][32];
    __shared__ unsigned short sB[128][32];

    const int tid = threadIdx.x;
    const int lane = tid & 63;
    const int wv = tid >> 6;
    const int wm = (wv >> 1) << 6;
    const int wn = (wv & 1) << 6;
    const int q = lane >> 4;
    const int c = lane & 15;

    const float* __restrict__ pB = W2 + (size_t)e * H_DIM * I_DIM + (size_t)(nt * 128) * I_DIM;

    f32x4 acc[4][4];
    const f32x4 zero = {0.0f, 0.0f, 0.0f, 0.0f};
    #pragma unroll
    for (int i = 0; i < 4; ++i)
        #pragma unroll
        for (int j = 0; j < 4; ++j) acc[i][j] = zero;

    const int srow = tid >> 2;
    const int schunk = (tid & 3) * 8;

    for (int kt = 0; kt < I_DIM; kt += 32) {
        __syncthreads();
        #pragma unroll
        for (int p = 0; p < 2; ++p) {
            int r = srow + p * 64;
            int slot = mt * 128 + r;
            u16x8 av = {0, 0, 0, 0, 0, 0, 0, 0};
            if (slot < ne)
                av = *(const u16x8*)(hbuf + (size_t)(off + slot) * I_DIM + kt + schunk);
            *(u16x8*)(&sA[r][schunk]) = av;

            const float* b = pB + (size_t)r * I_DIM + kt + schunk;
            float4 x0 = *(const float4*)(b);
            float4 x1 = *(const float4*)(b + 4);
            u16x8 bv;
            bv[0] = f2bf(x0.x); bv[1] = f2bf(x0.y); bv[2] = f2bf(x0.z); bv[3] = f2bf(x0.w);
            bv[4] = f2bf(x1.x); bv[5] = f2bf(x1.y); bv[6] = f2bf(x1.z); bv[7] = f2bf(x1.w);
            *(u16x8*)(&sB[r][schunk]) = bv;
        }
        __syncthreads();

        bf16x8 af[4], bfr[4];
        #pragma unroll
        for (int i = 0; i < 4; ++i)
            af[i] = *(const bf16x8*)(&sA[wm + i * 16 + c][q * 8]);
        #pragma unroll
        for (int j = 0; j < 4; ++j)
            bfr[j] = *(const bf16x8*)(&sB[wn + j * 16 + c][q * 8]);
        #pragma unroll
        for (int i = 0; i < 4; ++i)
            #pragma unroll
            for (int j = 0; j < 4; ++j)
                acc[i][j] = __builtin_amdgcn_mfma_f32_16x16x32_bf16(af[i], bfr[j], acc[i][j], 0, 0, 0);
    }

    #pragma unroll
    for (int i = 0; i < 4; ++i) {
        #pragma unroll
        for (int r = 0; r < 4; ++r) {
            int mloc = wm + i * 16 + q * 4 + r;
            int slot = mt * 128 + mloc;
            if (slot < ne) {
                int tok = btok[off + slot];
                float wgt = bw[off + slot];
                float* obase = out + (size_t)tok * H_DIM + nt * 128 + wn;
                #pragma unroll
                for (int j = 0; j < 4; ++j)
                    atomicAdd(obase + j * 16 + c, wgt * acc[i][j][r]);
            }
        }
    }
}

// ============================================================================

extern "C" void kernel_launch(void* const* d_in, const int* in_sizes, int n_in,
                              void* d_out, int out_size, void* d_ws, size_t ws_size,
                              hipStream_t stream) {
    const float* hs = (const float*)d_in[0];   // [T, H]
    const float* rl = (const float*)d_in[1];   // [T, E]
    const float* w1 = (const float*)d_in[2];   // [E, I, H]
    const float* w3 = (const float*)d_in[3];   // [E, I, H]
    const float* w2 = (const float*)d_in[4];   // [E, H, I]
    float* out = (float*)d_out;

    char* ws = (char*)d_ws;
    // meta region (first 1 MB)
    int*   counts   = (int*)(ws);
    int*   offsets  = (int*)(ws + 256);
    int*   btok     = (int*)(ws + 4096);            // 8192 ints
    float* bw       = (float*)(ws + 36864);         // 8192 floats
    int*   tok2slot = (int*)(ws + 69632);           // 8192 ints

    const size_t MB = 1ull << 20;
    const size_t NEED_A = 529 * MB;

    if (ws_size >= NEED_A) {
        // -------- Path A: preconvert weights to bf16, pipelined GEMMs -------
        unsigned short* Xb   = (unsigned short*)(ws + 1 * MB);     // 16 MB
        unsigned short* hbuf = (unsigned short*)(ws + 17 * MB);    // 64 MB
        float*          ybuf = (float*)(ws + 81 * MB);             // 64 MB
        unsigned short* w1b  = (unsigned short*)(ws + 145 * MB);   // 128 MB
        unsigned short* w3b  = (unsigned short*)(ws + 273 * MB);   // 128 MB
        unsigned short* w2b  = (unsigned short*)(ws + 401 * MB);   // 128 MB

        routing_kernel<<<1, 256, 0, stream>>>(rl, counts, offsets, btok, bw, tok2slot);

        cvt_kernel<<<(T_TOK * H_DIM / 4) / 256, 256, 0, stream>>>(hs, Xb);
        int wn4 = N_EXP * I_DIM * H_DIM / 4;   // 16M float4 per weight tensor
        cvt_kernel<<<wn4 / 256, 256, 0, stream>>>(w1, w1b);
        cvt_kernel<<<wn4 / 256, 256, 0, stream>>>(w3, w3b);
        cvt_kernel<<<wn4 / 256, 256, 0, stream>>>(w2, w2b);

        gemm1p_kernel<<<dim3(I_DIM / 128, 32, N_EXP), 512, 0, stream>>>(
            Xb, w1b, w3b, counts, offsets, btok, hbuf);

        gemm2p_kernel<<<dim3(H_DIM / 128, 32, N_EXP), 512, 0, stream>>>(
            hbuf, w2b, counts, offsets, ybuf);

        combine_kernel<<<(T_TOK * (H_DIM / 4)) / 256, 256, 0, stream>>>(
            ybuf, bw, tok2slot, out);
    } else {
        // -------- Path B: fallback (known-good round-1 structure) -----------
        unsigned short* Xb   = (unsigned short*)(ws + 1 * MB);            // 16 MB
        unsigned short* hbuf = (unsigned short*)(ws + 32 * MB);           // 64 MB

        hipMemsetAsync(out, 0, (size_t)T_TOK * H_DIM * sizeof(float), stream);

        routing_kernel<<<1, 256, 0, stream>>>(rl, counts, offsets, btok, bw, tok2slot);

        cvt_kernel<<<(T_TOK * H_DIM / 4) / 256, 256, 0, stream>>>(hs, Xb);

        gemm1_kernel<<<dim3(I_DIM / 128, T_TOK / 128, N_EXP), 256, 0, stream>>>(
            Xb, w1, w3, counts, offsets, btok, hbuf);

        gemm2_kernel<<<dim3(H_DIM / 128, T_TOK / 128, N_EXP), 256, 0, stream>>>(
            hbuf, w2, counts, offsets, btok, bw, out);
    }
}